// Round 5
// baseline (286.615 us; speedup 1.0000x reference)
//
#include <hip/hip_runtime.h>
#include <hip/hip_bf16.h>
#include <math.h>

// Attention block: y = out_proj(causal_softmax(rope(q)·rope(k)^T)·v)
// B=2 T=2048 C=2048 Hq=32 Hkv=8 D=64. bf16 MFMA, fp32 accumulate.
// R10: fix R9's causal-mask gate. R9 gated the diagonal-band mask on the
// wave's MAX q (kt*64+63 > qrow-l32+31); for wave 1 at kt=2qt and wave 3
// at kt=2qt+1 tile-max-key == wave-max-q so the branch was skipped, leaking
// unmasked future keys for lanes with q < wave-max (absmax 0.59). Gate on
// wave-MIN q instead (kt*64+63 > qrow-l32); the per-lane key>qrow check
// inside is exact, so over-application is harmless.
// attn: 32x32x16 MFMA, 4 waves x 32 q-rows, P in-register via
// pkbf+permlane32_swap (T12) -> zero P LDS traffic, 16 LDS reads : 16
// MFMA(32k FLOP) per tile per wave. GEMMs unchanged (XCD-swizzled 128x128).

typedef __attribute__((ext_vector_type(8))) short short8;
typedef __attribute__((ext_vector_type(4))) float f32x4;
typedef __attribute__((ext_vector_type(16))) float f32x16;
typedef __attribute__((ext_vector_type(2))) unsigned int uint2v;

#define MFMA16(a,b,c) __builtin_amdgcn_mfma_f32_16x16x32_bf16((a),(b),(c),0,0,0)
#define MFMA32(a,b,c) __builtin_amdgcn_mfma_f32_32x32x16_bf16((a),(b),(c),0,0,0)
#define QSCALE 0.18033688011112043f   // (1/sqrt(64))*log2(e): exp2-domain softmax
#define NFREQ  (-13.28771237954945f / 32.0f)  // -log2(10000)/32

__device__ __forceinline__ ushort f2bf(float f) {
  union { float f; unsigned u; } x; x.f = f;
  unsigned r = x.u + 0x7fffu + ((x.u >> 16) & 1u);   // RNE
  return (ushort)(r >> 16);
}
// round-half-up packed bf16 pair (5 int ops)
__device__ __forceinline__ uint pkbf(float a, float b) {
  union { float f; unsigned u; } x, y; x.f = a; y.f = b;
  return ((x.u + 0x8000u) >> 16) | ((y.u + 0x8000u) & 0xffff0000u);
}

__device__ __forceinline__ void g2l16(const void* g, void* l) {
  __builtin_amdgcn_global_load_lds(
      (__attribute__((address_space(1))) void*)g,
      (__attribute__((address_space(3))) void*)l, 16, 0, 0);
}

// one kernel for all fp32->bf16 conversions
__global__ void cvt_all(const float* __restrict__ x,  const float* __restrict__ wq,
                        const float* __restrict__ wk, const float* __restrict__ wv,
                        const float* __restrict__ wo,
                        ushort* __restrict__ x_bf, ushort* __restrict__ wqkv,
                        ushort* __restrict__ wo_bf) {
  int i = blockIdx.x * 256 + threadIdx.x;
  const float4* src; ushort* dst; int off;
  if (i < 2097152)      { src = (const float4*)x;  dst = x_bf;             off = i; }
  else if (i < 3145728) { src = (const float4*)wq; dst = wqkv;             off = i - 2097152; }
  else if (i < 3407872) { src = (const float4*)wk; dst = wqkv + 4194304;   off = i - 3145728; }
  else if (i < 3670016) { src = (const float4*)wv; dst = wqkv + 5242880;   off = i - 3407872; }
  else                  { src = (const float4*)wo; dst = wo_bf;            off = i - 3670016; }
  float4 v = src[off];
  ushort4 o;
  o.x = f2bf(v.x); o.y = f2bf(v.y); o.z = f2bf(v.z); o.w = f2bf(v.w);
  ((ushort4*)dst)[off] = o;
}

// QKV GEMM with fused RoPE/scatter epilogue. M=4096, N=3072, K=2048,
// grid (24,32) remapped so each XCD computes 96 contiguous tiles (4 y-rows):
// A-panels stay L2-local per XCD. Col-segment (swizzled bx): bx<16 -> q
// (rope+QSCALE -> qr), 16..19 -> k (rope -> kr), 20..23 -> v (-> vt).
__global__ __launch_bounds__(256, 3)
void gemm_qkv(const ushort* __restrict__ A, const ushort* __restrict__ Bw,
              const float* __restrict__ bq, const float* __restrict__ bk,
              const float* __restrict__ bv,
              ushort* __restrict__ qr, ushort* __restrict__ kr,
              ushort* __restrict__ vt) {
  const int K = 2048;
  __shared__ ushort As[2][128*32];
  __shared__ ushort Bs[2][128*32];
  const int tid = threadIdx.x;
  const int wave = tid >> 6, lane = tid & 63;
  const int wm = wave >> 1, wn = wave & 1;
  const int quad = lane >> 4, l16 = lane & 15;
  const int swg = (l16 >> 1) & 3;
  // bijective XCD remap: 768 blocks = 8 XCDs * 96 contiguous tiles
  int id = blockIdx.y * 24 + blockIdx.x;
  id = (id & 7) * 96 + (id >> 3);
  const int bx = id % 24, by = id / 24;
  const int m0 = by * 128, n0 = bx * 128;

  f32x4 acc[4][4] = {};

  auto stage = [&](int buf, int k0) {
#pragma unroll
    for (int i = 0; i < 2; ++i) {
      int cbase = (i*4 + wave) * 64;
      int p = cbase + lane;
      int row = p >> 2, pcb = p & 3;
      int cl = pcb ^ ((row >> 1) & 3);
      g2l16(A  + (size_t)(m0 + row) * K + k0 + cl * 8, As[buf] + (size_t)cbase * 8);
      g2l16(Bw + (size_t)(n0 + row) * K + k0 + cl * 8, Bs[buf] + (size_t)cbase * 8);
    }
  };

  stage(0, 0);
  for (int k0 = 0; k0 < K; k0 += 32) {
    __syncthreads();
    int cur = (k0 >> 5) & 1;
    if (k0 + 32 < K) stage(cur ^ 1, k0 + 32);

    short8 af[4], bfr[4];
#pragma unroll
    for (int mi = 0; mi < 4; ++mi)
      af[mi] = *(const short8*)(As[cur] + (wm*64 + mi*16 + l16)*32 + ((quad ^ swg) * 8));
#pragma unroll
    for (int ni = 0; ni < 4; ++ni)
      bfr[ni] = *(const short8*)(Bs[cur] + (wn*64 + ni*16 + l16)*32 + ((quad ^ swg) * 8));
#pragma unroll
    for (int mi = 0; mi < 4; ++mi)
#pragma unroll
      for (int ni = 0; ni < 4; ++ni)
        acc[mi][ni] = MFMA16(af[mi], bfr[ni], acc[mi][ni]);
  }

  // ---- fused epilogue ----
  const int bb = m0 >> 11;                 // batch (uniform per block)
  const int tb = (m0 & 2047) + wm*64;      // token base for this wave

  if (bx < 20) {
    // q or k: rope pairs are (acc[.][ni], acc[.][ni+2]) = features (d, d+32)
    const bool isq = bx < 16;
    const float scale = isq ? QSCALE : 1.0f;
#pragma unroll
    for (int ni = 0; ni < 2; ++ni) {
      int n = n0 + wn*64 + ni*16 + l16;
      int d = ni*16 + l16;                 // = n&63, < 32
      float bias1, bias2;
      ushort* dst;
      if (isq) {
        bias1 = bq[n]; bias2 = bq[n + 32];
        dst = qr + ((size_t)(bb*32 + (n >> 6)) * 2048) * 64 + d;
      } else {
        bias1 = bk[n - 2048]; bias2 = bk[n - 2016];
        dst = kr + ((size_t)(bb*8 + ((n >> 6) - 32)) * 2048) * 64 + d;
      }
      float invf = exp2f((float)d * NFREQ);
#pragma unroll
      for (int mi = 0; mi < 4; ++mi) {
#pragma unroll
        for (int r = 0; r < 4; ++r) {
          int t = tb + mi*16 + quad*4 + r;
          float x1 = acc[mi][ni][r]   + bias1;
          float x2 = acc[mi][ni+2][r] + bias2;
          float f = (float)t * invf;
          float sn = __sinf(f), cs = __cosf(f);
          dst[(size_t)t*64]      = f2bf((x1*cs - x2*sn) * scale);
          dst[(size_t)t*64 + 32] = f2bf((x2*cs + x1*sn) * scale);
        }
      }
    }
  } else {
    // v: write transposed vt[b][hkv][d][t]; 4 consecutive t per b64 store
#pragma unroll
    for (int ni = 0; ni < 4; ++ni) {
      int n = n0 + wn*64 + ni*16 + l16;
      int d = ni*16 + l16;                 // = n&63
      float bias = bv[n - 2560];
      ushort* dst = vt + ((size_t)(bb*8 + ((n - 2560) >> 6)) * 64 + d) * 2048;
#pragma unroll
      for (int mi = 0; mi < 4; ++mi) {
        int t = tb + mi*16 + quad*4;
        uint2 pk;
        pk.x = (uint)f2bf(acc[mi][ni][0]+bias) | ((uint)f2bf(acc[mi][ni][1]+bias) << 16);
        pk.y = (uint)f2bf(acc[mi][ni][2]+bias) | ((uint)f2bf(acc[mi][ni][3]+bias) << 16);
        *(uint2*)(dst + t) = pk;
      }
    }
  }
}

// 128x128 GEMM (output projection), BK=32, dbuf, fp32 out + bias.
// XCD remap: 512 blocks = 8 * 64 contiguous tiles.
__global__ __launch_bounds__(256, 3)
void gemm128(const ushort* __restrict__ A, const ushort* __restrict__ Bw,
             const float* __restrict__ b0,
             float* __restrict__ Cout, int M, int N, int K) {
  __shared__ ushort As[2][128*32];
  __shared__ ushort Bs[2][128*32];
  const int tid = threadIdx.x;
  const int wave = tid >> 6, lane = tid & 63;
  const int wm = wave >> 1, wn = wave & 1;
  const int quad = lane >> 4, l16 = lane & 15;
  const int swg = (l16 >> 1) & 3;
  int id = blockIdx.y * 16 + blockIdx.x;
  id = (id & 7) * 64 + (id >> 3);
  const int m0 = (id / 16) * 128, n0 = (id % 16) * 128;

  f32x4 acc[4][4] = {};

  auto stage = [&](int buf, int k0) {
#pragma unroll
    for (int i = 0; i < 2; ++i) {
      int cbase = (i*4 + wave) * 64;
      int p = cbase + lane;
      int row = p >> 2, pcb = p & 3;
      int cl = pcb ^ ((row >> 1) & 3);
      g2l16(A  + (size_t)(m0 + row) * K + k0 + cl * 8, As[buf] + (size_t)cbase * 8);
      g2l16(Bw + (size_t)(n0 + row) * K + k0 + cl * 8, Bs[buf] + (size_t)cbase * 8);
    }
  };

  stage(0, 0);
  for (int k0 = 0; k0 < K; k0 += 32) {
    __syncthreads();
    int cur = (k0 >> 5) & 1;
    if (k0 + 32 < K) stage(cur ^ 1, k0 + 32);

    short8 af[4], bfr[4];
#pragma unroll
    for (int mi = 0; mi < 4; ++mi)
      af[mi] = *(const short8*)(As[cur] + (wm*64 + mi*16 + l16)*32 + ((quad ^ swg) * 8));
#pragma unroll
    for (int ni = 0; ni < 4; ++ni)
      bfr[ni] = *(const short8*)(Bs[cur] + (wn*64 + ni*16 + l16)*32 + ((quad ^ swg) * 8));
#pragma unroll
    for (int mi = 0; mi < 4; ++mi)
#pragma unroll
      for (int ni = 0; ni < 4; ++ni)
        acc[mi][ni] = MFMA16(af[mi], bfr[ni], acc[mi][ni]);
  }

#pragma unroll
  for (int ni = 0; ni < 4; ++ni) {
    int n = n0 + wn*64 + ni*16 + l16;
    float bias = b0[n];
#pragma unroll
    for (int mi = 0; mi < 4; ++mi) {
#pragma unroll
      for (int r = 0; r < 4; ++r) {
        int m = m0 + wm*64 + mi*16 + quad*4 + r;
        Cout[(size_t)m * N + n] = acc[mi][ni][r] + bias;
      }
    }
  }
}

// Flash attention, causal, GQA, shift-free exp2 softmax. 32x32x16 MFMA.
// 4 waves x 32 q-rows = 128-row Q-tile; K/V tiles 64x64 in LDS (XOR-swizzle);
// P kept in-register via pkbf + permlane32_swap (no P LDS traffic).
// 32x32 C-layout: col = lane&31, row = (reg&3) + 8*(reg>>2) + 4*(lane>>5).
__global__ __launch_bounds__(256, 2)
void attn(const ushort* __restrict__ Q, const ushort* __restrict__ Kb,
          const ushort* __restrict__ Vt, ushort* __restrict__ Y) {
  __shared__ ushort Ks[2][64*64];
  __shared__ ushort Vs[2][64*64];
  const int tid = threadIdx.x, wave = tid >> 6, lane = tid & 63;
  const int l32 = lane & 31, hh = lane >> 5;
  const int h = blockIdx.y, b = blockIdx.z;
  const int hk = h >> 2;
  const ushort* Qb = Q  + ((size_t)(b*32 + h)  * 2048) * 64;
  const ushort* Kg = Kb + ((size_t)(b*8 + hk) * 2048) * 64;
  const ushort* Vg = Vt + ((size_t)(b*8 + hk) * 64) * 2048;

  // stage one 64x64 K tile + one 64x64 V tile; chunk-XOR swizzle on the
  // global source (LDS dest linear per global_load_lds rules)
  auto stage = [&](int buf, int kt) {
#pragma unroll
    for (int i = 0; i < 2; ++i) {
      int p = i*256 + tid;
      int row = p >> 3, pcb = p & 7;
      int cl = pcb ^ (row & 7);
      g2l16(Kg + (size_t)(kt*64 + row)*64 + cl*8, Ks[buf] + (size_t)p*8);
      g2l16(Vg + (size_t)row*2048 + kt*64 + cl*8, Vs[buf] + (size_t)p*8);
    }
  };

  for (int pass = 0; pass < 2; ++pass) {
    const int qt = pass ? (15 - blockIdx.x) : blockIdx.x;   // pair (qt, 15-qt)
    const int q0 = qt * 128;
    const int qrow = q0 + wave*32 + l32;
    // Q B-frags: for kstep ks, lane holds col q=qrow, d = ks*16 + hh*8 + j
    short8 qf[4];
#pragma unroll
    for (int ks = 0; ks < 4; ++ks)
      qf[ks] = *(const short8*)(Qb + (size_t)qrow*64 + ks*16 + hh*8);

    f32x16 o[2] = {};     // O^T: db*32 + rowmap = d, col = q
    float lsum = 0.f;

    __syncthreads();            // LDS reuse across passes
    stage(0, 0);

    const int ktmax = qt*2 + 1;
    for (int kt = 0; kt <= ktmax; ++kt) {
      __syncthreads();          // drain = prefetch issued one tile ago
      int cur = kt & 1;
      if (kt < ktmax) stage(cur ^ 1, kt + 1);

      // S^T = K Q^T: two 32x32 key-blocks, K=64 over 4 ksteps
      f32x16 s[2];
      __builtin_amdgcn_s_setprio(1);
#pragma unroll
      for (int kb = 0; kb < 2; ++kb) {
        f32x16 z = {};
#pragma unroll
        for (int ks = 0; ks < 4; ++ks) {
          int row = kb*32 + l32;
          short8 kf = *(const short8*)(Ks[cur] + row*64 + (((ks*2 + hh) ^ (row & 7)) * 8));
          z = MFMA32(kf, qf[ks], z);
        }
        s[kb] = z;
      }
      __builtin_amdgcn_s_setprio(0);

      // causal mask: gate on wave-MIN q (qrow - l32 = q0 + wave*32).
      // R9 bug: gating on wave-max q skipped needed masking for waves 1/3.
      if (kt*64 + 63 > qrow - l32) {
#pragma unroll
        for (int kb = 0; kb < 2; ++kb)
#pragma unroll
          for (int r = 0; r < 16; ++r) {
            int key = kt*64 + kb*32 + (r & 3) + 8*(r >> 2) + 4*hh;
            if (key > qrow) s[kb][r] = -INFINITY;
          }
      }

      // shift-free: p = exp2(s); exp2(-inf)=0 handles the mask
#pragma unroll
      for (int kb = 0; kb < 2; ++kb)
#pragma unroll
        for (int r = 0; r < 16; ++r) {
          s[kb][r] = __builtin_amdgcn_exp2f(s[kb][r]);
          lsum += s[kb][r];
        }

      // P -> bf16 B-frags in-register: for kstep c (keys kb*32+c*16+hh*8+{0..7})
      // u0,u2 = permlane32_swap(pk(s0,s1), pk(s4,s5)); u1,u3 = swap(pk(s2,s3), pk(s6,s7))
      __builtin_amdgcn_s_setprio(1);
#pragma unroll
      for (int kb = 0; kb < 2; ++kb) {
#pragma unroll
        for (int c = 0; c < 2; ++c) {
          int rb = c*8;
          uint a0 = pkbf(s[kb][rb+0], s[kb][rb+1]);
          uint b0 = pkbf(s[kb][rb+4], s[kb][rb+5]);
          uint a1 = pkbf(s[kb][rb+2], s[kb][rb+3]);
          uint b1 = pkbf(s[kb][rb+6], s[kb][rb+7]);
          uint2v r0 = __builtin_amdgcn_permlane32_swap(a0, b0, false, false);
          uint2v r1 = __builtin_amdgcn_permlane32_swap(a1, b1, false, false);
          union { uint u[4]; short8 s8; } pa;
          pa.u[0] = r0[0]; pa.u[1] = r1[0]; pa.u[2] = r0[1]; pa.u[3] = r1[1];
          // O^T += V^T P^T for this 16-key step
#pragma unroll
          for (int db = 0; db < 2; ++db) {
            int row = db*32 + l32;
            short8 vf = *(const short8*)(Vs[cur] + row*64 +
                          (((kb*4 + c*2 + hh) ^ (row & 7)) * 8));
            o[db] = MFMA32(vf, pa.s8, o[db]);
          }
        }
      }
      __builtin_amdgcn_s_setprio(0);
    }

    // combine denominator across lane halves (lanes l and l^32 share q-col)
    union { float f; uint u; } lu; lu.f = lsum;
    uint2v lr = __builtin_amdgcn_permlane32_swap(lu.u, lu.u, false, false);
    union { uint u; float f; } la, lb; la.u = lr[0]; lb.u = lr[1];
    float inv = 1.0f / (la.f + lb.f);

    // write Y[b][q][h*64 + d]: per db, 4 runs of 4 consecutive d
#pragma unroll
    for (int db = 0; db < 2; ++db) {
#pragma unroll
      for (int g = 0; g < 4; ++g) {
        int d = db*32 + 8*g + 4*hh;
        size_t base = ((size_t)(b*2048 + qrow)) * 2048 + h*64 + d;
        uint2 pk;
        pk.x = pkbf(o[db][4*g+0]*inv, o[db][4*g+1]*inv);
        pk.y = pkbf(o[db][4*g+2]*inv, o[db][4*g+3]*inv);
        *(uint2*)((ushort*)Y + base) = pk;
      }
    }
  }
}

extern "C" void kernel_launch(void* const* d_in, const int* in_sizes, int n_in,
                              void* d_out, int out_size, void* d_ws, size_t ws_size,
                              hipStream_t stream) {
  (void)in_sizes; (void)n_in; (void)out_size; (void)ws_size;
  const float* x  = (const float*)d_in[0];
  const float* Wq = (const float*)d_in[1];
  const float* bq = (const float*)d_in[2];
  const float* Wk = (const float*)d_in[3];
  const float* bk = (const float*)d_in[4];
  const float* Wv = (const float*)d_in[5];
  const float* bv = (const float*)d_in[6];
  const float* Wo = (const float*)d_in[7];
  const float* bo = (const float*)d_in[8];
  float* out = (float*)d_out;

  ushort* ws    = (ushort*)d_ws;
  ushort* x_bf  = ws;                        // 8388608
  ushort* wqkv  = x_bf + 8388608;            // 6291456  [3072][2048]
  ushort* wo_bf = wqkv + 6291456;            // 4194304
  ushort* qr    = wo_bf + 4194304;           // 8388608  [2][32][2048][64]
  ushort* kr    = qr + 8388608;              // 2097152  [2][8][2048][64]
  ushort* vt    = kr + 2097152;              // 2097152  [2][8][64][2048]
  ushort* Y     = x_bf;                      // x_bf dead after gemm_qkv

  cvt_all<<<18432, 256, 0, stream>>>(x, Wq, Wk, Wv, Wo, x_bf, wqkv, wo_bf);
  gemm_qkv<<<dim3(24, 32), 256, 0, stream>>>(x_bf, wqkv, bq, bk, bv, qr, kr, vt);
  attn<<<dim3(8, 32, 2), 256, 0, stream>>>(qr, kr, vt, Y);
  gemm128<<<dim3(16, 32), 256, 0, stream>>>(Y, wo_bf, bo, out, 4096, 2048, 2048);
}